// Round 3
// baseline (2633.055 us; speedup 1.0000x reference)
//
#include <hip/hip_runtime.h>

#define N 512
#define C 256

// k_edge v3 tiling: thread = 2 contiguous d x 16 j.
#define TJB 32   // j per block
#define JT  16   // j per thread
#define DT  2    // d per thread
// 256 threads = 128 d-groups (dg = t&127, d = 2dg,2dg+1) x 2 j-groups (jg = t>>7)

// Old fallback tiling:
#define TJ 16

__device__ __forceinline__ float f4c(const float4 v, const int i)
{
    return i == 0 ? v.x : i == 1 ? v.y : i == 2 ? v.z : v.w;
}

// ---------------------------------------------------------------------------
// Tiny tiled transpose: Wt[c][d] = W[d][c] for the three 256x256 weights.
// ---------------------------------------------------------------------------
__global__ __launch_bounds__(256) void k_transpose(
    const float* __restrict__ Wq, const float* __restrict__ Wk,
    const float* __restrict__ Wv, float* __restrict__ wt_base)
{
    __shared__ float tile[32][33];
    const float* W = blockIdx.z == 0 ? Wq : blockIdx.z == 1 ? Wk : Wv;
    float* Wt = wt_base + (size_t)blockIdx.z * C * C;
    const int tx  = threadIdx.x & 31;
    const int ty0 = threadIdx.x >> 5;      // 0..7
    const int bx = blockIdx.x * 32;        // c block
    const int by = blockIdx.y * 32;        // d block
    #pragma unroll
    for (int r = 0; r < 4; ++r)
        tile[ty0 + r * 8][tx] = W[(size_t)(by + ty0 + r * 8) * C + bx + tx];
    __syncthreads();
    #pragma unroll
    for (int r = 0; r < 4; ++r)
        Wt[(size_t)(bx + ty0 + r * 8) * C + by + tx] = tile[tx][ty0 + r * 8];
}

// ---------------------------------------------------------------------------
// Fused edge kernel v3: register-tiled edge GEMM, JT=16 / DT=2.
//  - e tile (32 j x 256 c, 32 KB LDS) staged once; reads are wave-uniform
//    broadcasts (jl depends only on the wave) -> near-free on the DS pipe.
//  - W consumed transposed as float2 (2 d per lane), lane-coalesced; JT=16
//    amortizes W L1 traffic to 0.25 B/FMA (32 B/cy/CU at full issue, under
//    the 64 B/cy L1 ceiling).
//  - Live set ~160 VGPR: fits architectural registers (no accvgpr spill),
//    explicit A/B double-buffer for W with static register sets.
// ---------------------------------------------------------------------------
template<bool WRITE_VE>
__global__ __launch_bounds__(256) void k_edge(
    const float* __restrict__ n_g, const float* __restrict__ s_g,
    const float* __restrict__ v_g,
    const float* __restrict__ wqt, const float* __restrict__ bq,
    const float* __restrict__ wkt, const float* __restrict__ bk,
    const float* __restrict__ wvt, const float* __restrict__ bv,
    float* __restrict__ scores, float* __restrict__ veW)
{
    __shared__ float e_lds[TJB][C];        // 32 KB
    __shared__ float part[4][JT];
    const int i  = blockIdx.x;
    const int jb = blockIdx.y * TJB;
    const int t  = threadIdx.x;
    const int dg = t & 127;                // d-pair group: d = 2dg, 2dg+1
    const int jg = t >> 7;                 // 0..1
    const int jl = jg * JT;                // local j base (wave-uniform)
    const int wv = t >> 6;                 // wave id 0..3
    const int lane = t & 63;

    // ---- stage e tile (coalesced along c) ----
    const float nic = n_g[i * C + t];
    #pragma unroll 4
    for (int j = 0; j < TJB; ++j) {
        const int jj = jb + j;
        e_lds[j][t] = nic * n_g[jj * C + t] * s_g[((size_t)i * N + jj) * C + t];
    }
    __syncthreads();

    // ---- accumulators ----
    float aq[DT][JT], ak[DT][JT], av[DT][JT];
    #pragma unroll
    for (int dr = 0; dr < DT; ++dr)
        #pragma unroll
        for (int jr = 0; jr < JT; ++jr) { aq[dr][jr] = 0.f; ak[dr][jr] = 0.f; av[dr][jr] = 0.f; }

    const float2* wq2 = (const float2*)wqt;   // float2 index: c*128 + dg
    const float2* wk2 = (const float2*)wkt;
    const float2* wv2 = (const float2*)wvt;

    // W double buffers (static register sets)
    float2 qA[4], kA[4], vA[4], qB[4], kB[4], vB[4];

    auto loadw = [&](float2 (&q)[4], float2 (&k)[4], float2 (&v)[4], int c4) {
        const int c0 = c4 * 4;
        #pragma unroll
        for (int cs = 0; cs < 4; ++cs) {
            q[cs] = wq2[(c0 + cs) * 128 + dg];
            k[cs] = wk2[(c0 + cs) * 128 + dg];
            if constexpr (WRITE_VE) v[cs] = wv2[(c0 + cs) * 128 + dg];
        }
    };
    auto comp = [&](const float2 (&q)[4], const float2 (&k)[4], const float2 (&v)[4], int c4) {
        #pragma unroll
        for (int jr = 0; jr < JT; ++jr) {
            const float4 ev = *(const float4*)&e_lds[jl + jr][c4 * 4];  // broadcast
            #pragma unroll
            for (int cs = 0; cs < 4; ++cs) {
                const float e = f4c(ev, cs);
                aq[0][jr] = fmaf(q[cs].x, e, aq[0][jr]);
                aq[1][jr] = fmaf(q[cs].y, e, aq[1][jr]);
                ak[0][jr] = fmaf(k[cs].x, e, ak[0][jr]);
                ak[1][jr] = fmaf(k[cs].y, e, ak[1][jr]);
                if constexpr (WRITE_VE) {
                    av[0][jr] = fmaf(v[cs].x, e, av[0][jr]);
                    av[1][jr] = fmaf(v[cs].y, e, av[1][jr]);
                }
            }
        }
    };

    loadw(qA, kA, vA, 0);
    for (int c8 = 0; c8 < C / 8; ++c8) {        // 32 iters, 2 c4-steps each
        const int c4a = 2 * c8, c4b = c4a + 1;
        loadw(qB, kB, vB, c4b);                 // prefetch B while computing A
        comp (qA, kA, vA, c4a);
        const int nxt = (c4b + 1 < C / 4) ? c4b + 1 : C / 4 - 1;
        loadw(qA, kA, vA, nxt);                 // prefetch A while computing B
        comp (qB, kB, vB, c4b);
    }

    // ---- epilogue ----
    const float2 bq2 = *(const float2*)&bq[2 * dg];
    const float2 bk2 = *(const float2*)&bk[2 * dg];
    float2 bv2;
    if constexpr (WRITE_VE) bv2 = *(const float2*)&bv[2 * dg];

    #pragma unroll
    for (int jr = 0; jr < JT; ++jr) {
        const int jj = jb + jl + jr;
        const size_t eoff = ((size_t)i * N + jj) * C + 2 * dg;
        const float2 vv = *(const float2*)&v_g[eoff];
        const float qh0 = aq[0][jr] + bq2.x, qh1 = aq[1][jr] + bq2.y;
        const float kh0 = ak[0][jr] + bk2.x, kh1 = ak[1][jr] + bk2.y;
        float r = qh0 * kh0 * vv.x * vv.x + qh1 * kh1 * vv.y * vv.y;
        if constexpr (WRITE_VE) {
            float2 veo;
            veo.x = (av[0][jr] + bv2.x) * vv.x;
            veo.y = (av[1][jr] + bv2.y) * vv.y;
            *(float2*)&veW[eoff] = veo;
        }
        #pragma unroll
        for (int off = 32; off > 0; off >>= 1)
            r += __shfl_down(r, off, 64);
        if (lane == 0) part[wv][jr] = r;        // wave w covers half the d-range
    }
    __syncthreads();
    if (t < 2 * JT) {
        const int g = t >> 4, jr = t & 15;      // g = j-group
        const float ssum = part[2 * g][jr] + part[2 * g + 1][jr];
        scores[(size_t)i * N + jb + g * JT + jr] = ssum * (1.0f / 16.0f); // 1/sqrt(256)
    }
}

// ---------------------------------------------------------------------------
// Row softmax, in place (512 cols, 256 threads -> 2 each). Unchanged.
// ---------------------------------------------------------------------------
__global__ __launch_bounds__(256) void k_softmax(float* __restrict__ buf)
{
    __shared__ float red[4];
    const int i = blockIdx.x;
    const int t = threadIdx.x;
    const int lane = t & 63, wid = t >> 6;

    const float a = buf[(size_t)i * N + t];
    const float b = buf[(size_t)i * N + t + 256];
    float m = fmaxf(a, b);
    #pragma unroll
    for (int off = 32; off > 0; off >>= 1)
        m = fmaxf(m, __shfl_xor(m, off, 64));
    if (lane == 0) red[wid] = m;
    __syncthreads();
    m = fmaxf(fmaxf(red[0], red[1]), fmaxf(red[2], red[3]));

    const float ea = __expf(a - m), eb = __expf(b - m);
    float ssum = ea + eb;
    #pragma unroll
    for (int off = 32; off > 0; off >>= 1)
        ssum += __shfl_xor(ssum, off, 64);
    __syncthreads();               // red reuse
    if (lane == 0) red[wid] = ssum;
    __syncthreads();
    const float inv = 1.0f / (red[0] + red[1] + red[2] + red[3]);
    buf[(size_t)i * N + t]       = ea * inv;
    buf[(size_t)i * N + t + 256] = eb * inv;
}

// ---------------------------------------------------------------------------
// Gather: x[i][d] = sum_j attn[i][j] * veW[i][j][d], residual + L2-normalize.
// ---------------------------------------------------------------------------
__global__ __launch_bounds__(256) void k_gather(
    const float* __restrict__ n_g, const float* __restrict__ veW,
    const float* __restrict__ attn, float* __restrict__ out)
{
    __shared__ float att_s[N];
    __shared__ float part[4];
    const int i = blockIdx.x;
    const int t = threadIdx.x;
    const int lane = t & 63, wid = t >> 6;

    att_s[t]       = attn[(size_t)i * N + t];
    att_s[t + 256] = attn[(size_t)i * N + t + 256];
    __syncthreads();

    const float* base = veW + (size_t)i * N * C + t;
    float xacc = 0.0f;
    for (int j = 0; j < N; j += 8) {
        const float p0 = base[(size_t)(j + 0) * C];
        const float p1 = base[(size_t)(j + 1) * C];
        const float p2 = base[(size_t)(j + 2) * C];
        const float p3 = base[(size_t)(j + 3) * C];
        const float p4 = base[(size_t)(j + 4) * C];
        const float p5 = base[(size_t)(j + 5) * C];
        const float p6 = base[(size_t)(j + 6) * C];
        const float p7 = base[(size_t)(j + 7) * C];
        xacc += att_s[j+0]*p0 + att_s[j+1]*p1 + att_s[j+2]*p2 + att_s[j+3]*p3
              + att_s[j+4]*p4 + att_s[j+5]*p5 + att_s[j+6]*p6 + att_s[j+7]*p7;
    }

    const float x = xacc + n_g[i * C + t];
    float sq = x * x;
    #pragma unroll
    for (int off = 32; off > 0; off >>= 1)
        sq += __shfl_xor(sq, off, 64);
    if (lane == 0) part[wid] = sq;
    __syncthreads();
    const float nrm = sqrtf(part[0] + part[1] + part[2] + part[3]);
    out[i * C + t] = x / nrm;
}

// ---------------------------------------------------------------------------
// Fallback (small-ws) kernels: previous session's structure, original W layout.
// ---------------------------------------------------------------------------
__global__ __launch_bounds__(256) void k_scores_old(
    const float* __restrict__ n_g, const float* __restrict__ s_g,
    const float* __restrict__ v_g,
    const float* __restrict__ Wq, const float* __restrict__ bq,
    const float* __restrict__ Wk, const float* __restrict__ bk,
    float* __restrict__ scores)
{
    __shared__ float e_lds[TJ][C];
    __shared__ float part[4][TJ];
    const int i  = blockIdx.x;
    const int jb = blockIdx.y * TJ;
    const int t  = threadIdx.x;
    const int lane = t & 63, wid = t >> 6;

    const float ni = n_g[i * C + t];
    #pragma unroll
    for (int j = 0; j < TJ; ++j) {
        const int jj = jb + j;
        e_lds[j][t] = ni * n_g[jj * C + t] * s_g[((size_t)i * N + jj) * C + t];
    }
    __syncthreads();

    float accq[TJ], acck[TJ];
    const float bqd = bq[t], bkd = bk[t];
    #pragma unroll
    for (int j = 0; j < TJ; ++j) { accq[j] = bqd; acck[j] = bkd; }

    const float4* wq4 = (const float4*)(Wq + (size_t)t * C);
    const float4* wk4 = (const float4*)(Wk + (size_t)t * C);
    for (int c4 = 0; c4 < C / 4; ++c4) {
        const float4 wq = wq4[c4];
        const float4 wk = wk4[c4];
        #pragma unroll
        for (int j = 0; j < TJ; ++j) {
            const float4 ev = *(const float4*)&e_lds[j][c4 * 4];
            accq[j] += wq.x*ev.x + wq.y*ev.y + wq.z*ev.z + wq.w*ev.w;
            acck[j] += wk.x*ev.x + wk.y*ev.y + wk.z*ev.z + wk.w*ev.w;
        }
    }

    #pragma unroll
    for (int j = 0; j < TJ; ++j) {
        const int jj = jb + j;
        const float vv = v_g[((size_t)i * N + jj) * C + t];
        float r = accq[j] * acck[j] * vv * vv;
        #pragma unroll
        for (int off = 32; off > 0; off >>= 1)
            r += __shfl_down(r, off, 64);
        if (lane == 0) part[wid][j] = r;
    }
    __syncthreads();
    if (t < TJ) {
        const float ssum = part[0][t] + part[1][t] + part[2][t] + part[3][t];
        scores[(size_t)i * N + jb + t] = ssum * (1.0f / 16.0f);
    }
}

__global__ __launch_bounds__(256) void k_out(
    const float* __restrict__ n_g, const float* __restrict__ s_g,
    const float* __restrict__ v_g,
    const float* __restrict__ Wv, const float* __restrict__ bv,
    const float* __restrict__ attn, float* __restrict__ out)
{
    __shared__ float e_lds[TJ][C];
    __shared__ float part[4];
    const int i = blockIdx.x;
    const int t = threadIdx.x;
    const int lane = t & 63, wid = t >> 6;

    const float ni  = n_g[i * C + t];
    const float bvd = bv[t];
    const float4* wv4 = (const float4*)(Wv + (size_t)t * C);
    float xacc = 0.0f;

    for (int jt = 0; jt < N / TJ; ++jt) {
        const int jb = jt * TJ;
        __syncthreads();
        #pragma unroll
        for (int j = 0; j < TJ; ++j) {
            const int jj = jb + j;
            e_lds[j][t] = ni * n_g[jj * C + t] * s_g[((size_t)i * N + jj) * C + t];
        }
        __syncthreads();

        float accv[TJ];
        #pragma unroll
        for (int j = 0; j < TJ; ++j) accv[j] = bvd;

        float4 vn = wv4[0];
        for (int c4 = 0; c4 < C / 4; ++c4) {
            const float4 wv = vn;
            if (c4 + 1 < C / 4) vn = wv4[c4 + 1];
            #pragma unroll
            for (int j = 0; j < TJ; ++j) {
                const float4 ev = *(const float4*)&e_lds[j][c4 * 4];
                accv[j] += wv.x*ev.x + wv.y*ev.y + wv.z*ev.z + wv.w*ev.w;
            }
        }
        #pragma unroll
        for (int j = 0; j < TJ; ++j) {
            const int jj = jb + j;
            const float a  = attn[(size_t)i * N + jj];
            const float vd = v_g[((size_t)i * N + jj) * C + t];
            xacc += a * accv[j] * vd;
        }
    }

    const float x = xacc + ni;
    float sq = x * x;
    #pragma unroll
    for (int off = 32; off > 0; off >>= 1)
        sq += __shfl_xor(sq, off, 64);
    if (lane == 0) part[wid] = sq;
    __syncthreads();
    const float nrm = sqrtf(part[0] + part[1] + part[2] + part[3]);
    out[i * C + t] = x / nrm;
}

extern "C" void kernel_launch(void* const* d_in, const int* in_sizes, int n_in,
                              void* d_out, int out_size, void* d_ws, size_t ws_size,
                              hipStream_t stream)
{
    const float* n_g = (const float*)d_in[0];
    const float* s_g = (const float*)d_in[1];
    const float* v_g = (const float*)d_in[2];
    const float* Wq  = (const float*)d_in[3];
    const float* bq  = (const float*)d_in[4];
    const float* Wk  = (const float*)d_in[5];
    const float* bk  = (const float*)d_in[6];
    const float* Wv  = (const float*)d_in[7];
    const float* bv  = (const float*)d_in[8];
    float* out = (float*)d_out;

    const size_t score_bytes = (size_t)N * N * sizeof(float);            // 1 MB
    const size_t ve_bytes    = (size_t)N * N * C * sizeof(float);        // 268 MB
    const size_t wt_bytes    = (size_t)3 * C * C * sizeof(float);        // 768 KB

    float* scores = (float*)d_ws;

    if (ws_size >= score_bytes + ve_bytes + wt_bytes) {
        float* veW = (float*)((char*)d_ws + score_bytes);
        float* wt  = (float*)((char*)d_ws + score_bytes + ve_bytes);
        float* wqt = wt;
        float* wkt = wt + (size_t)C * C;
        float* wvt = wt + (size_t)2 * C * C;

        k_transpose<<<dim3(C / 32, C / 32, 3), 256, 0, stream>>>(Wq, Wk, Wv, wt);
        k_edge<true><<<dim3(N, N / TJB), 256, 0, stream>>>(
            n_g, s_g, v_g, wqt, bq, wkt, bk, wvt, bv, scores, veW);
        k_softmax<<<N, 256, 0, stream>>>(scores);
        k_gather <<<N, 256, 0, stream>>>(n_g, veW, scores, out);
    } else if (ws_size >= score_bytes + wt_bytes) {
        float* wt  = (float*)((char*)d_ws + score_bytes);
        float* wqt = wt;
        float* wkt = wt + (size_t)C * C;
        float* wvt = wt + (size_t)2 * C * C;

        k_transpose<<<dim3(C / 32, C / 32, 3), 256, 0, stream>>>(Wq, Wk, Wv, wt);
        k_edge<false><<<dim3(N, N / TJB), 256, 0, stream>>>(
            n_g, s_g, v_g, wqt, bq, wkt, bk, wvt, bv, scores, nullptr);
        k_softmax<<<N, 256, 0, stream>>>(scores);
        k_out    <<<N, 256, 0, stream>>>(n_g, s_g, v_g, Wv, bv, scores, out);
    } else {
        k_scores_old<<<dim3(N, N / TJ), 256, 0, stream>>>(
            n_g, s_g, v_g, Wq, bq, Wk, bk, scores);
        k_softmax<<<N, 256, 0, stream>>>(scores);
        k_out    <<<N, 256, 0, stream>>>(n_g, s_g, v_g, Wv, bv, scores, out);
    }
}

// Round 4
// 2197.857 us; speedup vs baseline: 1.1980x; 1.1980x over previous
//
#include <hip/hip_runtime.h>

#define N 512
#define C 256

// k_edge v4 tiling: thread = 4 contiguous d x 4 j; wave = full 256-d range.
#define TJB 16   // j per block (4 waves x JT)
#define JT  4    // j per thread
#define DT  4    // d per thread (contiguous)
// 256 threads = 64 d-groups (dg = t&63, d = 4dg..4dg+3) x 4 j-groups (jg = wave)

// Old fallback tiling:
#define TJ 16

__device__ __forceinline__ float f4c(const float4 v, const int i)
{
    return i == 0 ? v.x : i == 1 ? v.y : i == 2 ? v.z : v.w;
}

// ---------------------------------------------------------------------------
// Tiny tiled transpose: Wt[c][d] = W[d][c] for the three 256x256 weights.
// ---------------------------------------------------------------------------
__global__ __launch_bounds__(256) void k_transpose(
    const float* __restrict__ Wq, const float* __restrict__ Wk,
    const float* __restrict__ Wv, float* __restrict__ wt_base)
{
    __shared__ float tile[32][33];
    const float* W = blockIdx.z == 0 ? Wq : blockIdx.z == 1 ? Wk : Wv;
    float* Wt = wt_base + (size_t)blockIdx.z * C * C;
    const int tx  = threadIdx.x & 31;
    const int ty0 = threadIdx.x >> 5;      // 0..7
    const int bx = blockIdx.x * 32;        // c block
    const int by = blockIdx.y * 32;        // d block
    #pragma unroll
    for (int r = 0; r < 4; ++r)
        tile[ty0 + r * 8][tx] = W[(size_t)(by + ty0 + r * 8) * C + bx + tx];
    __syncthreads();
    #pragma unroll
    for (int r = 0; r < 4; ++r)
        Wt[(size_t)(bx + ty0 + r * 8) * C + by + tx] = tile[tx][ty0 + r * 8];
}

// ---------------------------------------------------------------------------
// Fused edge kernel v4: register-tiled edge GEMM, DT=4 / JT=4.
//  - Live set ~90-100 regs (48 acc + 16 ev + 12 W transient): fits pure
//    VGPRs at 3 waves/SIMD -> no AGPR shuttle (round-2 bug), no occupancy
//    cliff (round-3 bug). Compiler schedules the unrolled cs body.
//  - e tile (16 j x 256 c, 16 KB LDS) staged once; reads are wave-uniform
//    broadcasts (4 ds_read_b128 per c4 per wave vs 384 FMA-cycles).
//  - W transposed (Wt[c][d]); lane dg loads float4 at d=4dg: coalesced,
//    identical across the 4 waves of the block -> L1-resident.
//    0.25 B/FMA = 32 B/cy/CU demand at full issue, under the 64 B/cy L1 ceiling.
//  - One wave covers all 256 d -> score reduce is a pure in-wave shuffle.
// ---------------------------------------------------------------------------
template<bool WRITE_VE>
__global__ __launch_bounds__(256, 3) void k_edge(
    const float* __restrict__ n_g, const float* __restrict__ s_g,
    const float* __restrict__ v_g,
    const float* __restrict__ wqt, const float* __restrict__ bq,
    const float* __restrict__ wkt, const float* __restrict__ bk,
    const float* __restrict__ wvt, const float* __restrict__ bv,
    float* __restrict__ scores, float* __restrict__ veW)
{
    __shared__ float e_lds[TJB][C];        // 16 KB
    const int i  = blockIdx.x;
    const int jb = blockIdx.y * TJB;
    const int t  = threadIdx.x;
    const int dg = t & 63;                 // d = 4dg .. 4dg+3
    const int jg = t >> 6;                 // wave id = j-group
    const int jl = jg * JT;                // local j base (wave-uniform)
    const int lane = t & 63;

    // ---- stage e tile (coalesced along c) ----
    const float nic = n_g[i * C + t];
    #pragma unroll 4
    for (int j = 0; j < TJB; ++j) {
        const int jj = jb + j;
        e_lds[j][t] = nic * n_g[jj * C + t] * s_g[((size_t)i * N + jj) * C + t];
    }
    __syncthreads();

    // ---- accumulators ----
    float aq[DT][JT], ak[DT][JT], av[DT][JT];
    #pragma unroll
    for (int dr = 0; dr < DT; ++dr)
        #pragma unroll
        for (int jr = 0; jr < JT; ++jr) { aq[dr][jr] = 0.f; ak[dr][jr] = 0.f; av[dr][jr] = 0.f; }

    const float4* wq4 = (const float4*)wqt;   // float4 index: c*64 + dg
    const float4* wk4 = (const float4*)wkt;
    const float4* wv4 = (const float4*)wvt;

    for (int c4 = 0; c4 < C / 4; ++c4) {
        // wave-uniform broadcast reads of the e tile (4 x b128)
        float4 ev[JT];
        #pragma unroll
        for (int jr = 0; jr < JT; ++jr)
            ev[jr] = *(const float4*)&e_lds[jl + jr][c4 * 4];

        #pragma unroll
        for (int cs = 0; cs < 4; ++cs) {
            const int c = c4 * 4 + cs;
            const float4 wq = wq4[c * 64 + dg];
            const float4 wk = wk4[c * 64 + dg];
            float4 wv;
            if constexpr (WRITE_VE) wv = wv4[c * 64 + dg];
            #pragma unroll
            for (int jr = 0; jr < JT; ++jr) {
                const float e = f4c(ev[jr], cs);
                #pragma unroll
                for (int dr = 0; dr < DT; ++dr) {
                    aq[dr][jr] = fmaf(f4c(wq, dr), e, aq[dr][jr]);
                    ak[dr][jr] = fmaf(f4c(wk, dr), e, ak[dr][jr]);
                    if constexpr (WRITE_VE)
                        av[dr][jr] = fmaf(f4c(wv, dr), e, av[dr][jr]);
                }
            }
        }
    }

    // ---- epilogue: bias, veW write, in-wave score reduce ----
    const float4 bq4 = *(const float4*)&bq[4 * dg];
    const float4 bk4 = *(const float4*)&bk[4 * dg];
    float4 bv4;
    if constexpr (WRITE_VE) bv4 = *(const float4*)&bv[4 * dg];

    #pragma unroll
    for (int jr = 0; jr < JT; ++jr) {
        const int jj = jb + jl + jr;
        const size_t eoff = ((size_t)i * N + jj) * C + 4 * dg;
        const float4 vv = *(const float4*)&v_g[eoff];
        float r = 0.f;
        float4 veo;
        #pragma unroll
        for (int dr = 0; dr < DT; ++dr) {
            const float qh = aq[dr][jr] + f4c(bq4, dr);
            const float kh = ak[dr][jr] + f4c(bk4, dr);
            const float vd = f4c(vv, dr);
            r += qh * kh * vd * vd;
            if constexpr (WRITE_VE) {
                const float vo = (av[dr][jr] + f4c(bv4, dr)) * vd;
                if (dr == 0) veo.x = vo; else if (dr == 1) veo.y = vo;
                else if (dr == 2) veo.z = vo; else veo.w = vo;
            }
        }
        if constexpr (WRITE_VE)
            *(float4*)&veW[eoff] = veo;
        #pragma unroll
        for (int off = 32; off > 0; off >>= 1)
            r += __shfl_down(r, off, 64);
        if (lane == 0)
            scores[(size_t)i * N + jj] = r * (1.0f / 16.0f);   // 1/sqrt(256)
    }
}

// ---------------------------------------------------------------------------
// Row softmax, in place (512 cols, 256 threads -> 2 each). Unchanged.
// ---------------------------------------------------------------------------
__global__ __launch_bounds__(256) void k_softmax(float* __restrict__ buf)
{
    __shared__ float red[4];
    const int i = blockIdx.x;
    const int t = threadIdx.x;
    const int lane = t & 63, wid = t >> 6;

    const float a = buf[(size_t)i * N + t];
    const float b = buf[(size_t)i * N + t + 256];
    float m = fmaxf(a, b);
    #pragma unroll
    for (int off = 32; off > 0; off >>= 1)
        m = fmaxf(m, __shfl_xor(m, off, 64));
    if (lane == 0) red[wid] = m;
    __syncthreads();
    m = fmaxf(fmaxf(red[0], red[1]), fmaxf(red[2], red[3]));

    const float ea = __expf(a - m), eb = __expf(b - m);
    float ssum = ea + eb;
    #pragma unroll
    for (int off = 32; off > 0; off >>= 1)
        ssum += __shfl_xor(ssum, off, 64);
    __syncthreads();               // red reuse
    if (lane == 0) red[wid] = ssum;
    __syncthreads();
    const float inv = 1.0f / (red[0] + red[1] + red[2] + red[3]);
    buf[(size_t)i * N + t]       = ea * inv;
    buf[(size_t)i * N + t + 256] = eb * inv;
}

// ---------------------------------------------------------------------------
// Gather: x[i][d] = sum_j attn[i][j] * veW[i][j][d], residual + L2-normalize.
// ---------------------------------------------------------------------------
__global__ __launch_bounds__(256) void k_gather(
    const float* __restrict__ n_g, const float* __restrict__ veW,
    const float* __restrict__ attn, float* __restrict__ out)
{
    __shared__ float att_s[N];
    __shared__ float part[4];
    const int i = blockIdx.x;
    const int t = threadIdx.x;
    const int lane = t & 63, wid = t >> 6;

    att_s[t]       = attn[(size_t)i * N + t];
    att_s[t + 256] = attn[(size_t)i * N + t + 256];
    __syncthreads();

    const float* base = veW + (size_t)i * N * C + t;
    float xacc = 0.0f;
    for (int j = 0; j < N; j += 8) {
        const float p0 = base[(size_t)(j + 0) * C];
        const float p1 = base[(size_t)(j + 1) * C];
        const float p2 = base[(size_t)(j + 2) * C];
        const float p3 = base[(size_t)(j + 3) * C];
        const float p4 = base[(size_t)(j + 4) * C];
        const float p5 = base[(size_t)(j + 5) * C];
        const float p6 = base[(size_t)(j + 6) * C];
        const float p7 = base[(size_t)(j + 7) * C];
        xacc += att_s[j+0]*p0 + att_s[j+1]*p1 + att_s[j+2]*p2 + att_s[j+3]*p3
              + att_s[j+4]*p4 + att_s[j+5]*p5 + att_s[j+6]*p6 + att_s[j+7]*p7;
    }

    const float x = xacc + n_g[i * C + t];
    float sq = x * x;
    #pragma unroll
    for (int off = 32; off > 0; off >>= 1)
        sq += __shfl_xor(sq, off, 64);
    if (lane == 0) part[wid] = sq;
    __syncthreads();
    const float nrm = sqrtf(part[0] + part[1] + part[2] + part[3]);
    out[i * C + t] = x / nrm;
}

// ---------------------------------------------------------------------------
// Fallback (small-ws) kernels: previous session's structure, original W layout.
// ---------------------------------------------------------------------------
__global__ __launch_bounds__(256) void k_scores_old(
    const float* __restrict__ n_g, const float* __restrict__ s_g,
    const float* __restrict__ v_g,
    const float* __restrict__ Wq, const float* __restrict__ bq,
    const float* __restrict__ Wk, const float* __restrict__ bk,
    float* __restrict__ scores)
{
    __shared__ float e_lds[TJ][C];
    __shared__ float part[4][TJ];
    const int i  = blockIdx.x;
    const int jb = blockIdx.y * TJ;
    const int t  = threadIdx.x;
    const int lane = t & 63, wid = t >> 6;

    const float ni = n_g[i * C + t];
    #pragma unroll
    for (int j = 0; j < TJ; ++j) {
        const int jj = jb + j;
        e_lds[j][t] = ni * n_g[jj * C + t] * s_g[((size_t)i * N + jj) * C + t];
    }
    __syncthreads();

    float accq[TJ], acck[TJ];
    const float bqd = bq[t], bkd = bk[t];
    #pragma unroll
    for (int j = 0; j < TJ; ++j) { accq[j] = bqd; acck[j] = bkd; }

    const float4* wq4 = (const float4*)(Wq + (size_t)t * C);
    const float4* wk4 = (const float4*)(Wk + (size_t)t * C);
    for (int c4 = 0; c4 < C / 4; ++c4) {
        const float4 wq = wq4[c4];
        const float4 wk = wk4[c4];
        #pragma unroll
        for (int j = 0; j < TJ; ++j) {
            const float4 ev = *(const float4*)&e_lds[j][c4 * 4];
            accq[j] += wq.x*ev.x + wq.y*ev.y + wq.z*ev.z + wq.w*ev.w;
            acck[j] += wk.x*ev.x + wk.y*ev.y + wk.z*ev.z + wk.w*ev.w;
        }
    }

    #pragma unroll
    for (int j = 0; j < TJ; ++j) {
        const int jj = jb + j;
        const float vv = v_g[((size_t)i * N + jj) * C + t];
        float r = accq[j] * acck[j] * vv * vv;
        #pragma unroll
        for (int off = 32; off > 0; off >>= 1)
            r += __shfl_down(r, off, 64);
        if (lane == 0) part[wid][j] = r;
    }
    __syncthreads();
    if (t < TJ) {
        const float ssum = part[0][t] + part[1][t] + part[2][t] + part[3][t];
        scores[(size_t)i * N + jb + t] = ssum * (1.0f / 16.0f);
    }
}

__global__ __launch_bounds__(256) void k_out(
    const float* __restrict__ n_g, const float* __restrict__ s_g,
    const float* __restrict__ v_g,
    const float* __restrict__ Wv, const float* __restrict__ bv,
    const float* __restrict__ attn, float* __restrict__ out)
{
    __shared__ float e_lds[TJ][C];
    __shared__ float part[4];
    const int i = blockIdx.x;
    const int t = threadIdx.x;
    const int lane = t & 63, wid = t >> 6;

    const float ni  = n_g[i * C + t];
    const float bvd = bv[t];
    const float4* wv4 = (const float4*)(Wv + (size_t)t * C);
    float xacc = 0.0f;

    for (int jt = 0; jt < N / TJ; ++jt) {
        const int jb = jt * TJ;
        __syncthreads();
        #pragma unroll
        for (int j = 0; j < TJ; ++j) {
            const int jj = jb + j;
            e_lds[j][t] = ni * n_g[jj * C + t] * s_g[((size_t)i * N + jj) * C + t];
        }
        __syncthreads();

        float accv[TJ];
        #pragma unroll
        for (int j = 0; j < TJ; ++j) accv[j] = bvd;

        float4 vn = wv4[0];
        for (int c4 = 0; c4 < C / 4; ++c4) {
            const float4 wv = vn;
            if (c4 + 1 < C / 4) vn = wv4[c4 + 1];
            #pragma unroll
            for (int j = 0; j < TJ; ++j) {
                const float4 ev = *(const float4*)&e_lds[j][c4 * 4];
                accv[j] += wv.x*ev.x + wv.y*ev.y + wv.z*ev.z + wv.w*ev.w;
            }
        }
        #pragma unroll
        for (int j = 0; j < TJ; ++j) {
            const int jj = jb + j;
            const float a  = attn[(size_t)i * N + jj];
            const float vd = v_g[((size_t)i * N + jj) * C + t];
            xacc += a * accv[j] * vd;
        }
    }

    const float x = xacc + ni;
    float sq = x * x;
    #pragma unroll
    for (int off = 32; off > 0; off >>= 1)
        sq += __shfl_xor(sq, off, 64);
    if (lane == 0) part[wid] = sq;
    __syncthreads();
    const float nrm = sqrtf(part[0] + part[1] + part[2] + part[3]);
    out[i * C + t] = x / nrm;
}

extern "C" void kernel_launch(void* const* d_in, const int* in_sizes, int n_in,
                              void* d_out, int out_size, void* d_ws, size_t ws_size,
                              hipStream_t stream)
{
    const float* n_g = (const float*)d_in[0];
    const float* s_g = (const float*)d_in[1];
    const float* v_g = (const float*)d_in[2];
    const float* Wq  = (const float*)d_in[3];
    const float* bq  = (const float*)d_in[4];
    const float* Wk  = (const float*)d_in[5];
    const float* bk  = (const float*)d_in[6];
    const float* Wv  = (const float*)d_in[7];
    const float* bv  = (const float*)d_in[8];
    float* out = (float*)d_out;

    const size_t score_bytes = (size_t)N * N * sizeof(float);            // 1 MB
    const size_t ve_bytes    = (size_t)N * N * C * sizeof(float);        // 268 MB
    const size_t wt_bytes    = (size_t)3 * C * C * sizeof(float);        // 768 KB

    float* scores = (float*)d_ws;

    if (ws_size >= score_bytes + ve_bytes + wt_bytes) {
        float* veW = (float*)((char*)d_ws + score_bytes);
        float* wt  = (float*)((char*)d_ws + score_bytes + ve_bytes);
        float* wqt = wt;
        float* wkt = wt + (size_t)C * C;
        float* wvt = wt + (size_t)2 * C * C;

        k_transpose<<<dim3(C / 32, C / 32, 3), 256, 0, stream>>>(Wq, Wk, Wv, wt);
        k_edge<true><<<dim3(N, N / TJB), 256, 0, stream>>>(
            n_g, s_g, v_g, wqt, bq, wkt, bk, wvt, bv, scores, veW);
        k_softmax<<<N, 256, 0, stream>>>(scores);
        k_gather <<<N, 256, 0, stream>>>(n_g, veW, scores, out);
    } else if (ws_size >= score_bytes + wt_bytes) {
        float* wt  = (float*)((char*)d_ws + score_bytes);
        float* wqt = wt;
        float* wkt = wt + (size_t)C * C;
        float* wvt = wt + (size_t)2 * C * C;

        k_transpose<<<dim3(C / 32, C / 32, 3), 256, 0, stream>>>(Wq, Wk, Wv, wt);
        k_edge<false><<<dim3(N, N / TJB), 256, 0, stream>>>(
            n_g, s_g, v_g, wqt, bq, wkt, bk, wvt, bv, scores, nullptr);
        k_softmax<<<N, 256, 0, stream>>>(scores);
        k_out    <<<N, 256, 0, stream>>>(n_g, s_g, v_g, Wv, bv, scores, out);
    } else {
        k_scores_old<<<dim3(N, N / TJ), 256, 0, stream>>>(
            n_g, s_g, v_g, Wq, bq, Wk, bk, scores);
        k_softmax<<<N, 256, 0, stream>>>(scores);
        k_out    <<<N, 256, 0, stream>>>(n_g, s_g, v_g, Wv, bv, scores, out);
    }
}